// Round 13
// baseline (511.483 us; speedup 1.0000x reference)
//
#include <hip/hip_runtime.h>

#define N_    50000
#define E_    320000
#define R_    16
#define B_    8
#define IN_   256
#define OUT_  256
#define EPR_  (E_ / R_)      // 20000 edges per relation
#define MBLK_ 157            // ceil(EPR_/128)
#define NBLK_ 391            // ceil(N_/128) selfloop tiles
#define SBLK_ 196            // ceil(N_/256) scan blocks
#define TIL_  (R_ * MBLK_ + NBLK_)   // 2903 tiles

typedef float  f32x16 __attribute__((ext_vector_type(16)));
typedef __bf16 bf16x8 __attribute__((ext_vector_type(8)));
typedef unsigned uint4v __attribute__((ext_vector_type(4)));

static __device__ __forceinline__ short f2bf(float f) {
  unsigned u = __float_as_uint(f);
  u = (u + 0x7FFFu + ((u >> 16) & 1u)) >> 16;   // RNE
  return (short)u;
}
static __device__ __forceinline__ float bf2f(unsigned short s) {
  return __uint_as_float(((unsigned)s) << 16);
}

// async global->LDS, 16B per lane; LDS dest = wave-uniform base + lane*16
static __device__ __forceinline__ void gl_lds16(const short* g, short* l) {
  __builtin_amdgcn_global_load_lds(
      (const __attribute__((address_space(1))) void*)g,
      (__attribute__((address_space(3))) void*)l, 16, 0, 0);
}

// ---------------------------------------------------------------------------
// prep: w_relT slots 0..15 = basis-composed weights (bf16, [o][i]); slot 16 =
// transposed loop_weight. feat -> bf16 (RNE). zero counts.
// ---------------------------------------------------------------------------
__global__ void prep_kernel(const float* __restrict__ feat, const float* __restrict__ weight,
                            const float* __restrict__ w_comp, const float* __restrict__ loop_w,
                            short* __restrict__ w_relT, short* __restrict__ feat_bf,
                            int* __restrict__ counts) {
  int gid = blockIdx.x * blockDim.x + threadIdx.x;
  int gsz = gridDim.x * blockDim.x;
  for (int idx = gid; idx < R_ * OUT_ * IN_; idx += gsz) {
    int r = idx >> 16, i = (idx >> 8) & 255, o = idx & 255;  // o fastest: coalesced weight reads
    float s = 0.f;
#pragma unroll
    for (int b = 0; b < B_; ++b)
      s += w_comp[r * B_ + b] * weight[(b * IN_ + i) * OUT_ + o];
    w_relT[(r * OUT_ + o) * IN_ + i] = f2bf(s);
  }
  for (int idx = gid; idx < OUT_ * IN_; idx += gsz) {
    int i = idx >> 8, o = idx & 255;
    w_relT[(R_ * OUT_ + o) * IN_ + i] = f2bf(loop_w[i * OUT_ + o]);   // slot 16
  }
  for (int idx = gid; idx < (N_ * IN_) / 4; idx += gsz) {
    float4 v = ((const float4*)feat)[idx];
    short4 s4;
    s4.x = f2bf(v.x); s4.y = f2bf(v.y); s4.z = f2bf(v.z); s4.w = f2bf(v.w);
    ((short4*)feat_bf)[idx] = s4;
  }
  for (int idx = gid; idx < N_; idx += gsz) counts[idx] = 0;
}

// ---------------------------------------------------------------------------
// reorder (r5-verified mapping, 17 slots): bake swizzled 16KB LDS stage-tiles
// into w_relS; the 8 tiles (2 halves x 4 stages) of one slot are contiguous.
// ---------------------------------------------------------------------------
__global__ void reorder_kernel(const short* __restrict__ w_relT, short* __restrict__ w_relS) {
  int idx = blockIdx.x * 256 + threadIdx.x;
  if (idx >= (R_ + 1) * OUT_ * IN_) return;
  int r = idx >> 16;
  int rem = idx & 65535;
  int half = rem >> 15;
  int stage = (rem >> 13) & 3;
  int c = (rem >> 3) & 1023;
  int j = rem & 7;
  int scol = c >> 3;
  int q = (c & 7) ^ (scol & 7);
  int o = (half << 7) + scol;
  int i = (stage << 6) + (q << 3) + j;
  w_relS[idx] = w_relT[((r << 8) + o) * IN_ + i];
}

// ---------------------------------------------------------------------------
// CSR build over counts[n]+1 (slot 0 of each node reserved for self edge)
// ---------------------------------------------------------------------------
__global__ void hist_kernel(const int* __restrict__ dst_idx, int* __restrict__ counts) {
  int e = blockIdx.x * 256 + threadIdx.x;
  if (e < E_) atomicAdd(&counts[dst_idx[e]], 1);
}

__global__ void scan1_kernel(const int* __restrict__ counts, int* __restrict__ offc,
                             int* __restrict__ bsum) {
  __shared__ int tmp[256];
  int tid = threadIdx.x;
  int gid = blockIdx.x * 256 + tid;
  int v = (gid < N_) ? counts[gid] + 1 : 0;
  tmp[tid] = v;
  __syncthreads();
  for (int d = 1; d < 256; d <<= 1) {
    int add = (tid >= d) ? tmp[tid - d] : 0;
    __syncthreads();
    tmp[tid] += add;
    __syncthreads();
  }
  if (gid < N_) offc[gid] = tmp[tid] - v;         // exclusive
  if (tid == 255) bsum[blockIdx.x] = tmp[255];
}

__global__ void scan2_kernel(int* __restrict__ bsum) {
  __shared__ int tmp[256];
  int tid = threadIdx.x;
  int v = (tid < SBLK_) ? bsum[tid] : 0;
  tmp[tid] = v;
  __syncthreads();
  for (int d = 1; d < 256; d <<= 1) {
    int add = (tid >= d) ? tmp[tid - d] : 0;
    __syncthreads();
    tmp[tid] += add;
    __syncthreads();
  }
  if (tid < SBLK_) bsum[tid] = tmp[tid] - v;      // exclusive
}

__global__ void scan3_kernel(int* __restrict__ offc, const int* __restrict__ bsum,
                             int* __restrict__ woff) {
  int gid = blockIdx.x * 256 + threadIdx.x;
  if (gid < N_) {
    int o = offc[gid] + bsum[blockIdx.x];
    offc[gid] = o;
    woff[gid] = o + 1;                            // slot 0 = self edge
  }
}

__global__ void scatter_kernel(const int* __restrict__ dst_idx, int* __restrict__ woff,
                               int* __restrict__ pos) {
  int e = blockIdx.x * 256 + threadIdx.x;
  if (e < E_) pos[e] = atomicAdd(&woff[dst_idx[e]], 1);
}

// ---------------------------------------------------------------------------
// edge (r12 GEMM core + packed-store epilogue + selfloop pseudo-relation):
// tiles < R_*MBLK_: relation r, random gather; tiles >= : slot 16 = selfloop
// (sequential gather, norm=1, msg slot = offc[node]).
// MODE=0 epilogue: acc*norm -> bf16 into chunk-XOR-swizzled LDS (reuse lds_w),
// then per-thread row segments stored as 8 x 16B nt dwordx4 (8x fewer store
// instructions, full-line writes). MODE=1: fp32 atomic fallback.
// ---------------------------------------------------------------------------
template <int MODE>
__launch_bounds__(256)
__global__ void edge_kernel(const short* __restrict__ feat_bf, const short* __restrict__ w_relS,
                            const float* __restrict__ norm, const int* __restrict__ src_idx,
                            const int* __restrict__ dst_idx, const int* __restrict__ pos,
                            const int* __restrict__ offc, short* __restrict__ msg,
                            float* __restrict__ acc_out) {
  __shared__ short lds_w[4 * 8192];      // 64KB: 4 stage-tiles of one (slot,half)
  int bid = blockIdx.x;
  int r, mblk, e0, rows;
  bool self;
  if (bid < R_ * MBLK_) {
    self = false;
    r = bid / MBLK_; mblk = bid - r * MBLK_;
    e0 = r * EPR_ + mblk * 128;
    int lim = EPR_ - mblk * 128; rows = lim > 128 ? 128 : lim;
  } else {
    self = true;
    r = R_; mblk = bid - R_ * MBLK_;
    e0 = mblk * 128;
    int lim = N_ - mblk * 128; rows = lim > 128 ? 128 : lim;
  }

  int tid = threadIdx.x;
  int lane = tid & 63, wave = tid >> 6;
  int lm = lane & 31, hi = lane >> 5;
  int wr = wave << 5;

  int erow = wr + lm;
  int eg   = e0 + (erow < rows ? erow : 0);      // clamped: garbage rows never stored
  int src  = self ? eg : src_idx[eg];
  const bf16x8* __restrict__ arow = (const bf16x8*)(feat_bf + (size_t)src * IN_);

  // ---- gather the lane's A half-row ONCE: 16 x 16B, all in flight at once
  bf16x8 a[16];
#pragma unroll
  for (int i = 0; i < 16; ++i) a[i] = arow[2 * i + hi];

  // ---- per-row norm (t-indexed, applied before bf16 conversion)
  float nr[16];
#pragma unroll
  for (int t = 0; t < 16; ++t) {
    int row = (t & 3) + ((t >> 2) << 3) + (hi << 2);
    int er  = wr + row;
    int ee  = e0 + (er < rows ? er : 0);
    nr[t] = self ? 1.f : norm[ee];
  }

  const short* wt = w_relS + (size_t)r * 65536;

#pragma unroll
  for (int h = 0; h < 2; ++h) {
    if (h == 1) __syncthreads();        // epilogue reads of lds_w done before restage
#pragma unroll
    for (int j = 0; j < 16; ++j) {
      int chunk = (wave << 4) + j;
      gl_lds16(wt + h * 32768 + chunk * 512 + lane * 8, &lds_w[chunk * 512]);
    }

    f32x16 acc[4];
#pragma unroll
    for (int g = 0; g < 4; ++g)
#pragma unroll
      for (int t = 0; t < 16; ++t) acc[g][t] = 0.f;

    __syncthreads();                    // drains A regs (h=0) + W half h

#pragma unroll
    for (int stage = 0; stage < 4; ++stage) {
      const short* lb = &lds_w[stage * 8192];
#pragma unroll
      for (int s = 0; s < 4; ++s) {
        bf16x8 af = a[stage * 4 + s];
        int q = s * 2 + hi;
#pragma unroll
        for (int g = 0; g < 4; ++g) {
          int col = (g << 5) + lm;
          bf16x8 bfr = *(const bf16x8*)(&lb[col * 64 + ((q ^ (col & 7)) << 3)]);
          acc[g] = __builtin_amdgcn_mfma_f32_32x32x16_bf16(af, bfr, acc[g], 0, 0, 0);
        }
      }
    }

    if (MODE == 0) {
      __syncthreads();                  // all waves done reading lds_w -> reuse as transpose tile
      // write acc (bf16, *norm) into swizzled [128 rows][128 cols] tile
#pragma unroll
      for (int g = 0; g < 4; ++g) {
#pragma unroll
        for (int t = 0; t < 16; ++t) {
          int row = wr + (t & 3) + ((t >> 2) << 3) + (hi << 2);
          int col = (g << 5) + lm;
          int cs  = (col >> 3) ^ (row & 15);
          lds_w[row * 128 + (cs << 3) + (col & 7)] = f2bf(acc[g][t] * nr[t]);
        }
      }
      __syncthreads();
      // read back row segments, 8 x 16B nt stores per thread (full-line writes)
      int row = tid >> 1, p = tid & 1;
      if (row < rows) {
        int ee = e0 + row;
        int pr = self ? offc[ee] : pos[ee];
        size_t mo = (size_t)pr * OUT_ + h * 128 + p * 64;   // shorts
#pragma unroll
        for (int k = 0; k < 8; ++k) {
          int c  = (p << 3) + k;
          int cs = c ^ (row & 15);
          uint4v v = *(const uint4v*)(&lds_w[row * 128 + (cs << 3)]);
          __builtin_nontemporal_store(v, (uint4v*)(&msg[mo + (k << 3)]));
        }
      }
    } else {
      // fallback: element-wise fp32 atomics
#pragma unroll
      for (int g = 0; g < 4; ++g) {
#pragma unroll
        for (int t = 0; t < 16; ++t) {
          int row = (t & 3) + ((t >> 2) << 3) + (hi << 2);
          int er  = wr + row;
          if (er < rows) {
            int ee = e0 + er;
            int d  = (self ? ee : dst_idx[ee]) * OUT_ + h * 128 + (g << 5) + lm;
            unsafeAtomicAdd(&acc_out[(size_t)d], acc[g][t] * nr[t]);
          }
        }
      }
    }
  }
}

// ---------------------------------------------------------------------------
// agg: node range = [offc[n], offc[n]+counts[n]+1) incl. self slot.
// Streaming reads; fp32 accumulate; + bias, ReLU, write out.
// ---------------------------------------------------------------------------
__launch_bounds__(256)
__global__ void agg_kernel(const short* __restrict__ msg, const int* __restrict__ offc,
                           const int* __restrict__ counts, const float* __restrict__ h_bias,
                           float* __restrict__ out) {
  int n = blockIdx.x * 4 + (threadIdx.x >> 6);
  if (n >= N_) return;
  int lane = threadIdx.x & 63;
  int off = offc[n], cnt = counts[n] + 1;
  float4 a = make_float4(0.f, 0.f, 0.f, 0.f);
  const unsigned long long* __restrict__ m8 = (const unsigned long long*)msg; // row = 64 x 8B
  for (int j = 0; j < cnt; ++j) {
    unsigned long long v = __builtin_nontemporal_load(&m8[(size_t)(off + j) * 64 + lane]);
    a.x += bf2f((unsigned short)(v & 0xffffu));
    a.y += bf2f((unsigned short)((v >> 16) & 0xffffu));
    a.z += bf2f((unsigned short)((v >> 32) & 0xffffu));
    a.w += bf2f((unsigned short)(v >> 48));
  }
  float4 b = ((const float4*)h_bias)[lane];
  a.x = fmaxf(a.x + b.x, 0.f);
  a.y = fmaxf(a.y + b.y, 0.f);
  a.z = fmaxf(a.z + b.z, 0.f);
  a.w = fmaxf(a.w + b.w, 0.f);
  ((float4*)out)[(size_t)n * 64 + lane] = a;
}

// fallback helpers
__global__ void zero_out_kernel(float* __restrict__ out) {
  int idx = blockIdx.x * 256 + threadIdx.x;
  if (idx < N_ * OUT_ / 4)
    ((float4*)out)[idx] = make_float4(0.f, 0.f, 0.f, 0.f);
}
__global__ void bias_relu_kernel(float* __restrict__ out, const float* __restrict__ h_bias) {
  int idx = blockIdx.x * 256 + threadIdx.x;
  if (idx < N_ * OUT_ / 4) {
    float4 v = ((float4*)out)[idx];
    float4 b = ((const float4*)h_bias)[idx & 63];
    v.x = fmaxf(v.x + b.x, 0.f);
    v.y = fmaxf(v.y + b.y, 0.f);
    v.z = fmaxf(v.z + b.z, 0.f);
    v.w = fmaxf(v.w + b.w, 0.f);
    ((float4*)out)[idx] = v;
  }
}

// ---------------------------------------------------------------------------
extern "C" void kernel_launch(void* const* d_in, const int* in_sizes, int n_in,
                              void* d_out, int out_size, void* d_ws, size_t ws_size,
                              hipStream_t stream) {
  const float* feat    = (const float*)d_in[0];
  const float* weight  = (const float*)d_in[1];
  const float* w_comp  = (const float*)d_in[2];
  const float* loop_w  = (const float*)d_in[3];
  const float* h_bias  = (const float*)d_in[4];
  const float* norm    = (const float*)d_in[5];
  const int*   src_idx = (const int*)d_in[6];
  const int*   dst_idx = (const int*)d_in[7];
  float* out = (float*)d_out;

  short* w_relT  = (short*)d_ws;                        // 17 slots = 2.23 MB
  short* w_relS  = w_relT + (R_ + 1) * OUT_ * IN_;      // 2.23 MB
  short* feat_bf = w_relS + (R_ + 1) * OUT_ * IN_;      // 25.6 MB
  int*   counts  = (int*)(feat_bf + (size_t)N_ * IN_);  // 200 KB
  int*   offc    = counts + N_;                         // 200 KB
  int*   woff    = offc + N_;                           // 200 KB
  int*   bsum    = woff + N_;                           // 1 KB
  int*   pos     = bsum + 256;                          // 1.28 MB
  short* msg     = (short*)(pos + E_);                  // (E+N)*256 bf16 = 189.4 MB
  size_t need    = (size_t)((char*)(msg + (size_t)(E_ + N_) * OUT_) - (char*)d_ws);

  prep_kernel<<<1024, 256, 0, stream>>>(feat, weight, w_comp, loop_w,
                                        w_relT, feat_bf, counts);
  reorder_kernel<<<((R_ + 1) * OUT_ * IN_) / 256, 256, 0, stream>>>(w_relT, w_relS);
  hist_kernel<<<(E_ + 255) / 256, 256, 0, stream>>>(dst_idx, counts);
  scan1_kernel<<<SBLK_, 256, 0, stream>>>(counts, offc, bsum);
  scan2_kernel<<<1, 256, 0, stream>>>(bsum);
  scan3_kernel<<<SBLK_, 256, 0, stream>>>(offc, bsum, woff);
  scatter_kernel<<<(E_ + 255) / 256, 256, 0, stream>>>(dst_idx, woff, pos);

  if (ws_size >= need) {
    edge_kernel<0><<<TIL_, 256, 0, stream>>>(feat_bf, w_relS, norm, src_idx, dst_idx,
                                             pos, offc, msg, nullptr);
    agg_kernel<<<(N_ + 3) / 4, 256, 0, stream>>>(msg, offc, counts, h_bias, out);
  } else {
    zero_out_kernel<<<(N_ * OUT_ / 4 + 255) / 256, 256, 0, stream>>>(out);
    edge_kernel<1><<<TIL_, 256, 0, stream>>>(feat_bf, w_relS, norm, src_idx, dst_idx,
                                             nullptr, offc, nullptr, out);
    bias_relu_kernel<<<(N_ * OUT_ / 4 + 255) / 256, 256, 0, stream>>>(out, h_bias);
  }
}

// Round 14
// 218.515 us; speedup vs baseline: 2.3407x; 2.3407x over previous
//
#include <hip/hip_runtime.h>

#define N_    50000
#define E_    320000
#define R_    16
#define B_    8
#define IN_   256
#define OUT_  256
#define EPR_  (E_ / R_)      // 20000 edges per relation
#define MBLK_ 157            // ceil(EPR_/128)
#define NBLK_ 391            // ceil(N_/128) selfloop tiles
#define SBLK_ 196            // ceil(N_/256) scan blocks
#define TIL_  (R_ * MBLK_ + NBLK_)   // 2903 tiles

typedef float  f32x16 __attribute__((ext_vector_type(16)));
typedef __bf16 bf16x8 __attribute__((ext_vector_type(8)));

static __device__ __forceinline__ short f2bf(float f) {
  unsigned u = __float_as_uint(f);
  u = (u + 0x7FFFu + ((u >> 16) & 1u)) >> 16;   // RNE
  return (short)u;
}
static __device__ __forceinline__ float bf2f(unsigned short s) {
  return __uint_as_float(((unsigned)s) << 16);
}

// async global->LDS, 16B per lane; LDS dest = wave-uniform base + lane*16
static __device__ __forceinline__ void gl_lds16(const short* g, short* l) {
  __builtin_amdgcn_global_load_lds(
      (const __attribute__((address_space(1))) void*)g,
      (__attribute__((address_space(3))) void*)l, 16, 0, 0);
}

// ---------------------------------------------------------------------------
// prep: w_relT slots 0..15 = basis-composed weights (bf16, [o][i]); slot 16 =
// transposed loop_weight. feat -> bf16 (RNE). zero counts.
// ---------------------------------------------------------------------------
__global__ void prep_kernel(const float* __restrict__ feat, const float* __restrict__ weight,
                            const float* __restrict__ w_comp, const float* __restrict__ loop_w,
                            short* __restrict__ w_relT, short* __restrict__ feat_bf,
                            int* __restrict__ counts) {
  int gid = blockIdx.x * blockDim.x + threadIdx.x;
  int gsz = gridDim.x * blockDim.x;
  for (int idx = gid; idx < R_ * OUT_ * IN_; idx += gsz) {
    int r = idx >> 16, i = (idx >> 8) & 255, o = idx & 255;  // o fastest: coalesced weight reads
    float s = 0.f;
#pragma unroll
    for (int b = 0; b < B_; ++b)
      s += w_comp[r * B_ + b] * weight[(b * IN_ + i) * OUT_ + o];
    w_relT[(r * OUT_ + o) * IN_ + i] = f2bf(s);
  }
  for (int idx = gid; idx < OUT_ * IN_; idx += gsz) {
    int i = idx >> 8, o = idx & 255;
    w_relT[(R_ * OUT_ + o) * IN_ + i] = f2bf(loop_w[i * OUT_ + o]);   // slot 16
  }
  for (int idx = gid; idx < (N_ * IN_) / 4; idx += gsz) {
    float4 v = ((const float4*)feat)[idx];
    short4 s4;
    s4.x = f2bf(v.x); s4.y = f2bf(v.y); s4.z = f2bf(v.z); s4.w = f2bf(v.w);
    ((short4*)feat_bf)[idx] = s4;
  }
  for (int idx = gid; idx < N_; idx += gsz) counts[idx] = 0;
}

// ---------------------------------------------------------------------------
// reorder (r5-verified mapping, 17 slots): bake swizzled 16KB LDS stage-tiles
// into w_relS; the 8 tiles (2 halves x 4 stages) of one slot are contiguous.
// ---------------------------------------------------------------------------
__global__ void reorder_kernel(const short* __restrict__ w_relT, short* __restrict__ w_relS) {
  int idx = blockIdx.x * 256 + threadIdx.x;
  if (idx >= (R_ + 1) * OUT_ * IN_) return;
  int r = idx >> 16;
  int rem = idx & 65535;
  int half = rem >> 15;
  int stage = (rem >> 13) & 3;
  int c = (rem >> 3) & 1023;
  int j = rem & 7;
  int scol = c >> 3;
  int q = (c & 7) ^ (scol & 7);
  int o = (half << 7) + scol;
  int i = (stage << 6) + (q << 3) + j;
  w_relS[idx] = w_relT[((r << 8) + o) * IN_ + i];
}

// ---------------------------------------------------------------------------
// CSR build over counts[n]+1 (slot 0 of each node reserved for self edge)
// ---------------------------------------------------------------------------
__global__ void hist_kernel(const int* __restrict__ dst_idx, int* __restrict__ counts) {
  int e = blockIdx.x * 256 + threadIdx.x;
  if (e < E_) atomicAdd(&counts[dst_idx[e]], 1);
}

__global__ void scan1_kernel(const int* __restrict__ counts, int* __restrict__ offc,
                             int* __restrict__ bsum) {
  __shared__ int tmp[256];
  int tid = threadIdx.x;
  int gid = blockIdx.x * 256 + tid;
  int v = (gid < N_) ? counts[gid] + 1 : 0;
  tmp[tid] = v;
  __syncthreads();
  for (int d = 1; d < 256; d <<= 1) {
    int add = (tid >= d) ? tmp[tid - d] : 0;
    __syncthreads();
    tmp[tid] += add;
    __syncthreads();
  }
  if (gid < N_) offc[gid] = tmp[tid] - v;         // exclusive
  if (tid == 255) bsum[blockIdx.x] = tmp[255];
}

__global__ void scan2_kernel(int* __restrict__ bsum) {
  __shared__ int tmp[256];
  int tid = threadIdx.x;
  int v = (tid < SBLK_) ? bsum[tid] : 0;
  tmp[tid] = v;
  __syncthreads();
  for (int d = 1; d < 256; d <<= 1) {
    int add = (tid >= d) ? tmp[tid - d] : 0;
    __syncthreads();
    tmp[tid] += add;
    __syncthreads();
  }
  if (tid < SBLK_) bsum[tid] = tmp[tid] - v;      // exclusive
}

__global__ void scan3_kernel(int* __restrict__ offc, const int* __restrict__ bsum,
                             int* __restrict__ woff) {
  int gid = blockIdx.x * 256 + threadIdx.x;
  if (gid < N_) {
    int o = offc[gid] + bsum[blockIdx.x];
    offc[gid] = o;
    woff[gid] = o + 1;                            // slot 0 = self edge
  }
}

__global__ void scatter_kernel(const int* __restrict__ dst_idx, int* __restrict__ woff,
                               int* __restrict__ pos) {
  int e = blockIdx.x * 256 + threadIdx.x;
  if (e < E_) pos[e] = atomicAdd(&woff[dst_idx[e]], 1);
}

// ---------------------------------------------------------------------------
// edge (EXACT r12 GEMM core + r12 2B-store epilogue; + selfloop pseudo-rel):
// tiles < R_*MBLK_: relation r (random gather, norm, msg slot pos[e]);
// tiles >= : slot 16 selfloop (sequential gather, norm=1, msg slot offc[n]).
// One block per 128 rows computes BOTH 128-col halves sequentially (gather once).
// MODE=0: per-element bf16 nt stores (L2-merged full lines — r12-verified);
// MODE=1: fp32 atomic fallback into acc_out.
// ---------------------------------------------------------------------------
template <int MODE>
__launch_bounds__(256)
__global__ void edge_kernel(const short* __restrict__ feat_bf, const short* __restrict__ w_relS,
                            const float* __restrict__ norm, const int* __restrict__ src_idx,
                            const int* __restrict__ dst_idx, const int* __restrict__ pos,
                            const int* __restrict__ offc, short* __restrict__ msg,
                            float* __restrict__ acc_out) {
  __shared__ short lds_w[4 * 8192];      // 64KB: 4 stage-tiles of one (slot,half)
  int bid = blockIdx.x;
  int r, mblk, e0, rows;
  bool self;
  if (bid < R_ * MBLK_) {
    self = false;
    r = bid / MBLK_; mblk = bid - r * MBLK_;
    e0 = r * EPR_ + mblk * 128;
    int lim = EPR_ - mblk * 128; rows = lim > 128 ? 128 : lim;
  } else {
    self = true;
    r = R_; mblk = bid - R_ * MBLK_;
    e0 = mblk * 128;
    int lim = N_ - mblk * 128; rows = lim > 128 ? 128 : lim;
  }

  int tid = threadIdx.x;
  int lane = tid & 63, wave = tid >> 6;
  int lm = lane & 31, hi = lane >> 5;
  int wr = wave << 5;

  int erow = wr + lm;
  int eg   = e0 + (erow < rows ? erow : 0);      // clamped: garbage rows never stored
  int src  = self ? eg : src_idx[eg];
  const bf16x8* __restrict__ arow = (const bf16x8*)(feat_bf + (size_t)src * IN_);

  // ---- gather the lane's A half-row ONCE: 16 x 16B, all in flight at once
  bf16x8 a[16];
#pragma unroll
  for (int i = 0; i < 16; ++i) a[i] = arow[2 * i + hi];

  // ---- epilogue metadata (shared by both halves; r12-verified mapping)
  float nr[16]; int er_ok[16]; int prow[16]; int db[16];
#pragma unroll
  for (int t = 0; t < 16; ++t) {
    int row = (t & 3) + ((t >> 2) << 3) + (hi << 2);
    int er  = wr + row;
    int ee  = e0 + (er < rows ? er : 0);
    er_ok[t] = (er < rows);
    nr[t]    = self ? 1.f : norm[ee];
    prow[t]  = (MODE == 0) ? (self ? offc[ee] : pos[ee]) : 0;
    db[t]    = (self ? ee : dst_idx[ee]) * OUT_;
  }

  const short* wt = w_relS + (size_t)r * 65536;

#pragma unroll
  for (int h = 0; h < 2; ++h) {
    if (h == 1) __syncthreads();        // all waves done reading lds_w (half 0)
#pragma unroll
    for (int j = 0; j < 16; ++j) {
      int chunk = (wave << 4) + j;
      gl_lds16(wt + h * 32768 + chunk * 512 + lane * 8, &lds_w[chunk * 512]);
    }

    f32x16 acc[4];
#pragma unroll
    for (int g = 0; g < 4; ++g)
#pragma unroll
      for (int t = 0; t < 16; ++t) acc[g][t] = 0.f;

    __syncthreads();                    // drains A regs (h=0) + W half h

#pragma unroll
    for (int stage = 0; stage < 4; ++stage) {
      const short* lb = &lds_w[stage * 8192];
#pragma unroll
      for (int s = 0; s < 4; ++s) {
        bf16x8 af = a[stage * 4 + s];
        int q = s * 2 + hi;
#pragma unroll
        for (int g = 0; g < 4; ++g) {
          int col = (g << 5) + lm;
          bf16x8 bfr = *(const bf16x8*)(&lb[col * 64 + ((q ^ (col & 7)) << 3)]);
          acc[g] = __builtin_amdgcn_mfma_f32_32x32x16_bf16(af, bfr, acc[g], 0, 0, 0);
        }
      }
    }

    // ---- epilogue half h (EXACT r12): row t = edge, col = h*128 + g*32 + lm
#pragma unroll
    for (int g = 0; g < 4; ++g) {
      int col = h * 128 + (g << 5) + lm;
#pragma unroll
      for (int t = 0; t < 16; ++t) {
        if (er_ok[t]) {
          float v = acc[g][t] * nr[t];
          if (MODE == 0)
            __builtin_nontemporal_store(f2bf(v), &msg[(size_t)prow[t] * OUT_ + col]);
          else
            unsafeAtomicAdd(&acc_out[(size_t)db[t] + col], v);
        }
      }
    }
  }
}

// ---------------------------------------------------------------------------
// agg: node range = [offc[n], offc[n]+counts[n]+1) incl. self slot (CSR-
// contiguous, streaming). fp32 accumulate; + bias, ReLU, write out.
// ---------------------------------------------------------------------------
__launch_bounds__(256)
__global__ void agg_kernel(const short* __restrict__ msg, const int* __restrict__ offc,
                           const int* __restrict__ counts, const float* __restrict__ h_bias,
                           float* __restrict__ out) {
  int n = blockIdx.x * 4 + (threadIdx.x >> 6);
  if (n >= N_) return;
  int lane = threadIdx.x & 63;
  int off = offc[n], cnt = counts[n] + 1;
  float4 a = make_float4(0.f, 0.f, 0.f, 0.f);
  const unsigned long long* __restrict__ m8 = (const unsigned long long*)msg; // row = 64 x 8B
  for (int j = 0; j < cnt; ++j) {
    unsigned long long v = __builtin_nontemporal_load(&m8[(size_t)(off + j) * 64 + lane]);
    a.x += bf2f((unsigned short)(v & 0xffffu));
    a.y += bf2f((unsigned short)((v >> 16) & 0xffffu));
    a.z += bf2f((unsigned short)((v >> 32) & 0xffffu));
    a.w += bf2f((unsigned short)(v >> 48));
  }
  float4 b = ((const float4*)h_bias)[lane];
  a.x = fmaxf(a.x + b.x, 0.f);
  a.y = fmaxf(a.y + b.y, 0.f);
  a.z = fmaxf(a.z + b.z, 0.f);
  a.w = fmaxf(a.w + b.w, 0.f);
  ((float4*)out)[(size_t)n * 64 + lane] = a;
}

// fallback helpers
__global__ void zero_out_kernel(float* __restrict__ out) {
  int idx = blockIdx.x * 256 + threadIdx.x;
  if (idx < N_ * OUT_ / 4)
    ((float4*)out)[idx] = make_float4(0.f, 0.f, 0.f, 0.f);
}
__global__ void bias_relu_kernel(float* __restrict__ out, const float* __restrict__ h_bias) {
  int idx = blockIdx.x * 256 + threadIdx.x;
  if (idx < N_ * OUT_ / 4) {
    float4 v = ((float4*)out)[idx];
    float4 b = ((const float4*)h_bias)[idx & 63];
    v.x = fmaxf(v.x + b.x, 0.f);
    v.y = fmaxf(v.y + b.y, 0.f);
    v.z = fmaxf(v.z + b.z, 0.f);
    v.w = fmaxf(v.w + b.w, 0.f);
    ((float4*)out)[idx] = v;
  }
}

// ---------------------------------------------------------------------------
extern "C" void kernel_launch(void* const* d_in, const int* in_sizes, int n_in,
                              void* d_out, int out_size, void* d_ws, size_t ws_size,
                              hipStream_t stream) {
  const float* feat    = (const float*)d_in[0];
  const float* weight  = (const float*)d_in[1];
  const float* w_comp  = (const float*)d_in[2];
  const float* loop_w  = (const float*)d_in[3];
  const float* h_bias  = (const float*)d_in[4];
  const float* norm    = (const float*)d_in[5];
  const int*   src_idx = (const int*)d_in[6];
  const int*   dst_idx = (const int*)d_in[7];
  float* out = (float*)d_out;

  short* w_relT  = (short*)d_ws;                        // 17 slots = 2.23 MB
  short* w_relS  = w_relT + (R_ + 1) * OUT_ * IN_;      // 2.23 MB
  short* feat_bf = w_relS + (R_ + 1) * OUT_ * IN_;      // 25.6 MB
  int*   counts  = (int*)(feat_bf + (size_t)N_ * IN_);  // 200 KB
  int*   offc    = counts + N_;                         // 200 KB
  int*   woff    = offc + N_;                           // 200 KB
  int*   bsum    = woff + N_;                           // 1 KB
  int*   pos     = bsum + 256;                          // 1.28 MB
  short* msg     = (short*)(pos + E_);                  // (E+N)*256 bf16 = 189.4 MB
  size_t need    = (size_t)((char*)(msg + (size_t)(E_ + N_) * OUT_) - (char*)d_ws);

  prep_kernel<<<1024, 256, 0, stream>>>(feat, weight, w_comp, loop_w,
                                        w_relT, feat_bf, counts);
  reorder_kernel<<<((R_ + 1) * OUT_ * IN_) / 256, 256, 0, stream>>>(w_relT, w_relS);
  hist_kernel<<<(E_ + 255) / 256, 256, 0, stream>>>(dst_idx, counts);
  scan1_kernel<<<SBLK_, 256, 0, stream>>>(counts, offc, bsum);
  scan2_kernel<<<1, 256, 0, stream>>>(bsum);
  scan3_kernel<<<SBLK_, 256, 0, stream>>>(offc, bsum, woff);
  scatter_kernel<<<(E_ + 255) / 256, 256, 0, stream>>>(dst_idx, woff, pos);

  if (ws_size >= need) {
    edge_kernel<0><<<TIL_, 256, 0, stream>>>(feat_bf, w_relS, norm, src_idx, dst_idx,
                                             pos, offc, msg, nullptr);
    agg_kernel<<<(N_ + 3) / 4, 256, 0, stream>>>(msg, offc, counts, h_bias, out);
  } else {
    zero_out_kernel<<<(N_ * OUT_ / 4 + 255) / 256, 256, 0, stream>>>(out);
    edge_kernel<1><<<TIL_, 256, 0, stream>>>(feat_bf, w_relS, norm, src_idx, dst_idx,
                                             nullptr, offc, nullptr, out);
    bias_relu_kernel<<<(N_ * OUT_ / 4 + 255) / 256, 256, 0, stream>>>(out, h_bias);
  }
}